// Round 7
// baseline (360.741 us; speedup 1.0000x reference)
//
#include <hip/hip_runtime.h>
#include <hip/hip_bf16.h>
#include <cstddef>

// Problem constants (B=2, N=2048, D=2048, H=16, HKV=4, HD=128, G=4)
#define NB    2
#define NSEQ  2048
#define DMODEL 2048
#define NH    16
#define NKV   4
#define HDIM  128

typedef __attribute__((ext_vector_type(8))) short short8;
typedef __attribute__((ext_vector_type(4))) short short4v;
typedef __attribute__((ext_vector_type(4))) float floatx4;
typedef const __attribute__((address_space(1))) void* gptr_t;
typedef __attribute__((address_space(3))) void* lptr_t;

#if __has_builtin(__builtin_amdgcn_exp2f)
#define EXP2F(x) __builtin_amdgcn_exp2f(x)
#else
#define EXP2F(x) __expf((x) * 0.6931471805599453f)
#endif

__device__ inline unsigned short f2bf(float f) {
    // RTNE f32 -> bf16
    unsigned int u = __float_as_uint(f);
    u += 0x7fffu + ((u >> 16) & 1u);
    return (unsigned short)(u >> 16);
}

// pack two f32 -> two bf16 (truncating) in ONE v_perm_b32
__device__ inline unsigned int pk2bf_trunc(float a, float b) {
    return __builtin_amdgcn_perm(__float_as_uint(b), __float_as_uint(a), 0x07060302u);
}

__device__ inline floatx4 fzero4() {
    floatx4 v; v[0] = 0.f; v[1] = 0.f; v[2] = 0.f; v[3] = 0.f; return v;
}

// ---- merged prep: x cast, Wq/Wkv/Wo transpose+cast, mask->bias2 -----------
__global__ void prep_k(const float* __restrict__ x, const float* __restrict__ Wq,
                       const float* __restrict__ Wkv, const float* __restrict__ Wo,
                       const float* __restrict__ mask,
                       unsigned short* __restrict__ xb,
                       unsigned short* __restrict__ W1T,
                       unsigned short* __restrict__ WoT,
                       float* __restrict__ bias2) {
    __shared__ float tile[32][33];
    const int bid = blockIdx.x, t = threadIdx.x;
    if (bid < 8192) {  // cast x: 8192 blocks x 256 thr x float4
        int i = bid * 256 + t;
        float4 v = ((const float4*)x)[i];
        ushort4 o;
        o.x = f2bf(v.x); o.y = f2bf(v.y); o.z = f2bf(v.z); o.w = f2bf(v.w);
        ((ushort4*)xb)[i] = o;
        return;
    }
    if (bid >= 18432) {  // bias2 = (1-mask) * -1e9*log2e : 4 blocks
        int i = (bid - 18432) * 1024 + t * 4;
        float4 m = *(const float4*)(mask + i);
        const float c = -1.4426950408889634e9f;
        float4 o;
        o.x = (1.f - m.x) * c; o.y = (1.f - m.y) * c;
        o.z = (1.f - m.z) * c; o.w = (1.f - m.w) * c;
        *(float4*)(bias2 + i) = o;
        return;
    }
    // transposes (LDS 32x32 tiles, 32x8 thread layout)
    const float* W; unsigned short* Wt; int N, local;
    if (bid < 12288)      { W = Wq;  Wt = W1T;                       N = 2048; local = bid - 8192; }
    else if (bid < 14336) { W = Wkv; Wt = W1T + (size_t)2048 * 2048; N = 1024; local = bid - 12288; }
    else                  { W = Wo;  Wt = WoT;                       N = 2048; local = bid - 14336; }
    const int K = 2048;
    int nt = N >> 5;
    int bx = local % nt, by = local / nt;
    int n0 = bx * 32, k0 = by * 32, tx = t & 31, ty = t >> 5;
#pragma unroll
    for (int i = 0; i < 4; i++)
        tile[ty + i * 8][tx] = W[(size_t)(k0 + ty + i * 8) * N + n0 + tx];
    __syncthreads();
#pragma unroll
    for (int i = 0; i < 4; i++)
        Wt[(size_t)(n0 + ty + i * 8) * K + k0 + tx] = f2bf(tile[tx][ty + i * 8]);
}

// ---------------- m97-style bf16 GEMM, B-transposed input ------------------
// 1D grid + T1 XCD-chunked swizzle (nwg%8==0 -> bijective): each XCD gets a
// contiguous wgid chunk so neighbor tiles (sharing A/B panels) hit its L2.
__global__ __launch_bounds__(256, 3) void gemm_bt(
    const unsigned short* __restrict__ A,
    const unsigned short* __restrict__ Bt,
    float* __restrict__ C,
    const float* __restrict__ bias,
    int M, int N, int K) {
    __shared__ __align__(16) unsigned short As[128 * 32];
    __shared__ __align__(16) unsigned short Bs[128 * 32];
    const int t = threadIdx.x;
    const int chunk = gridDim.x >> 3;
    const int wgid = (blockIdx.x & 7) * chunk + (blockIdx.x >> 3);
    const int nx = N >> 7;
    const int m0 = (wgid / nx) * 128, n0 = (wgid % nx) * 128;
    const int lane = t & 63, wave = t >> 6;
    const int ln = lane & 15, quad = lane >> 4;
    const int wm = (wave >> 1) * 64, wn = (wave & 1) * 64;
    floatx4 acc[4][4];
#pragma unroll
    for (int r = 0; r < 4; r++)
#pragma unroll
        for (int c = 0; c < 4; c++) acc[r][c] = fzero4();

    const int r0 = t >> 2, c0 = (t & 3) * 8;
    const int r1 = (t + 256) >> 2, c1 = ((t + 256) & 3) * 8;

    for (int kt = 0; kt < K; kt += 32) {
        const unsigned short* ga0 = A + (size_t)(m0 + r0) * K + kt + c0;
        const unsigned short* ga1 = A + (size_t)(m0 + r1) * K + kt + c1;
        const unsigned short* gb0 = Bt + (size_t)(n0 + r0) * K + kt + c0;
        const unsigned short* gb1 = Bt + (size_t)(n0 + r1) * K + kt + c1;
        __builtin_amdgcn_global_load_lds((gptr_t)ga0, (lptr_t)(As + t * 8), 16, 0, 0);
        __builtin_amdgcn_global_load_lds((gptr_t)ga1, (lptr_t)(As + (t + 256) * 8), 16, 0, 0);
        __builtin_amdgcn_global_load_lds((gptr_t)gb0, (lptr_t)(Bs + t * 8), 16, 0, 0);
        __builtin_amdgcn_global_load_lds((gptr_t)gb1, (lptr_t)(Bs + (t + 256) * 8), 16, 0, 0);
        __syncthreads();
        short8 af[4], bfr[4];
#pragma unroll
        for (int r = 0; r < 4; r++)
            af[r] = *(const short8*)(As + (wm + r * 16 + ln) * 32 + quad * 8);
#pragma unroll
        for (int c = 0; c < 4; c++)
            bfr[c] = *(const short8*)(Bs + (wn + c * 16 + ln) * 32 + quad * 8);
#pragma unroll
        for (int r = 0; r < 4; r++)
#pragma unroll
            for (int c = 0; c < 4; c++)
                acc[r][c] = __builtin_amdgcn_mfma_f32_16x16x32_bf16(af[r], bfr[c], acc[r][c], 0, 0, 0);
        __syncthreads();
    }
#pragma unroll
    for (int r = 0; r < 4; r++) {
        int mb = m0 + wm + r * 16 + quad * 4;
#pragma unroll
        for (int c = 0; c < 4; c++) {
            int col = n0 + wn + c * 16 + ln;
            float bv = bias ? bias[col] : 0.f;
#pragma unroll
            for (int g = 0; g < 4; g++)
                C[(size_t)(mb + g) * N + col] = acc[r][c][g] + bv;
        }
    }
}

// ------- fused projection GEMM + RoPE + Q/K/V layout (bf16 outputs) --------
// 1D grid (768 = 8 XCD x 96) + T1 chunked swizzle, same decode as gemm_bt.
__global__ __launch_bounds__(256, 3) void gemm_qkv_rope(
    const unsigned short* __restrict__ A,    // xb (4096 x 2048)
    const unsigned short* __restrict__ Bt,   // W1T (3072 x 2048)
    const float* __restrict__ cosb,          // (N,64)
    const float* __restrict__ sinb,          // (N,64)
    unsigned short* __restrict__ Qb,
    unsigned short* __restrict__ Kb,
    unsigned short* __restrict__ Vt) {
    const int K = DMODEL;
    __shared__ __align__(16) unsigned short As[128 * 32];
    __shared__ __align__(16) unsigned short Bs[128 * 32];
    __shared__ __align__(16) unsigned short Vx[128 * 136];  // v-transpose tile
    const int t = threadIdx.x;
    const int wgid = (blockIdx.x & 7) * 96 + (blockIdx.x >> 3);
    const int m0 = (wgid / 24) * 128, n0 = (wgid % 24) * 128;
    const int lane = t & 63, wave = t >> 6;
    const int ln = lane & 15, quad = lane >> 4;
    const int wm = (wave >> 1) * 64, bq = (wave & 1) * 32;
    floatx4 acc[4][4];
#pragma unroll
    for (int r = 0; r < 4; r++)
#pragma unroll
        for (int c = 0; c < 4; c++) acc[r][c] = fzero4();

    const int r0 = t >> 2, c0 = (t & 3) * 8;
    const int r1 = (t + 256) >> 2, c1 = ((t + 256) & 3) * 8;

    for (int kt = 0; kt < K; kt += 32) {
        const unsigned short* ga0 = A + (size_t)(m0 + r0) * K + kt + c0;
        const unsigned short* ga1 = A + (size_t)(m0 + r1) * K + kt + c1;
        const unsigned short* gb0 = Bt + (size_t)(n0 + r0) * K + kt + c0;
        const unsigned short* gb1 = Bt + (size_t)(n0 + r1) * K + kt + c1;
        __builtin_amdgcn_global_load_lds((gptr_t)ga0, (lptr_t)(As + t * 8), 16, 0, 0);
        __builtin_amdgcn_global_load_lds((gptr_t)ga1, (lptr_t)(As + (t + 256) * 8), 16, 0, 0);
        __builtin_amdgcn_global_load_lds((gptr_t)gb0, (lptr_t)(Bs + t * 8), 16, 0, 0);
        __builtin_amdgcn_global_load_lds((gptr_t)gb1, (lptr_t)(Bs + (t + 256) * 8), 16, 0, 0);
        __syncthreads();
        short8 af[4], bfr[4];
#pragma unroll
        for (int r = 0; r < 4; r++)
            af[r] = *(const short8*)(As + (wm + r * 16 + ln) * 32 + quad * 8);
#pragma unroll
        for (int c = 0; c < 4; c++)
            bfr[c] = *(const short8*)(
                Bs + (bq + (c & 1) * 16 + (c >> 1) * 64 + ln) * 32 + quad * 8);
#pragma unroll
        for (int r = 0; r < 4; r++)
#pragma unroll
            for (int c = 0; c < 4; c++)
                acc[r][c] = __builtin_amdgcn_mfma_f32_16x16x32_bf16(af[r], bfr[c], acc[r][c], 0, 0, 0);
        __syncthreads();
    }

    // ---------------- epilogue ----------------
    if (n0 < 2048) {
        const float qs = (float)(0.08838834764831845 * 1.4426950408889634);
        int h = n0 >> 7;
#pragma unroll
        for (int r = 0; r < 4; r++)
#pragma unroll
            for (int c = 0; c < 2; c++)
#pragma unroll
                for (int g = 0; g < 4; g++) {
                    int row = m0 + wm + r * 16 + quad * 4 + g;
                    int b = row >> 11, n = row & 2047;
                    int j = bq + c * 16 + ln;
                    float cv = cosb[n * 64 + j], sv = sinb[n * 64 + j];
                    float t1 = acc[r][c][g], t2 = acc[r][c + 2][g];
                    unsigned short* qp = Qb + ((size_t)(b * NH + h) * NSEQ + n) * 128;
                    qp[j]      = f2bf((t1 * cv + t2 * sv) * qs);
                    qp[j + 64] = f2bf((t2 * cv - t1 * sv) * qs);
                }
    } else if (n0 < 2560) {
        int hk = (n0 - 2048) >> 7;
#pragma unroll
        for (int r = 0; r < 4; r++)
#pragma unroll
            for (int c = 0; c < 2; c++)
#pragma unroll
                for (int g = 0; g < 4; g++) {
                    int row = m0 + wm + r * 16 + quad * 4 + g;
                    int b = row >> 11, n = row & 2047;
                    int j = bq + c * 16 + ln;
                    float cv = cosb[n * 64 + j], sv = sinb[n * 64 + j];
                    float t1 = acc[r][c][g], t2 = acc[r][c + 2][g];
                    unsigned short* kp = Kb + ((size_t)(b * NKV + hk) * NSEQ + n) * 128;
                    kp[j]      = f2bf(t1 * cv + t2 * sv);
                    kp[j + 64] = f2bf(t2 * cv - t1 * sv);
                }
    } else {
        int hk = (n0 - 2560) >> 7;
#pragma unroll
        for (int r = 0; r < 4; r++)
#pragma unroll
            for (int c = 0; c < 4; c++) {
                int d = bq + (c & 1) * 16 + (c >> 1) * 64 + ln;
                int s = wm + (r >> 1) * 32 + quad * 8 + (r & 1) * 4;
#pragma unroll
                for (int g = 0; g < 4; g++)
                    Vx[d * 136 + s + g] = f2bf(acc[r][c][g]);
            }
        __syncthreads();
        int b = m0 >> 11, nloc = m0 & 2047;
#pragma unroll
        for (int pass = 0; pass < 2; pass++) {
            int d = pass * 64 + (t >> 2), q4 = t & 3;
            unsigned short* vp =
                Vt + ((size_t)(b * NKV + hk) * 128 + d) * NSEQ + nloc + q4 * 32;
#pragma unroll
            for (int i = 0; i < 4; i++)
                *(short8*)(vp + i * 8) = *(const short8*)(Vx + d * 136 + q4 * 32 + i * 8);
        }
    }
}

// ---- flash attention (v10 = r6 v9 + qb_base split for instrumentation) ----
// Two 512-block launches (qb 0-15 / 16-31) so the GEMM kernels surface in
// the top-5 profile with their counters.  Body identical to r6 (best: 84.7us
// at 1024 blocks): 2 waves x 32 q-rows, bias-as-C-init, T5 setprio.
__global__ __launch_bounds__(128, 2) void attn_k(
    const unsigned short* __restrict__ Qb,   // (B,H,N,HD)
    const unsigned short* __restrict__ Kb,   // (B,HKV,N,HD)
    const unsigned short* __restrict__ Vt,   // (B,HKV,HD,N) permuted cols
    const float* __restrict__ bias2,         // (B,N) = (1-mask)*-1e9*log2e
    unsigned short* __restrict__ Ab,         // (B,N,H*HD) bf16
    int qb_base) {
    __shared__ __align__(16) unsigned short Ks[2 * 32 * 128];  // 16 KB
    __shared__ __align__(16) unsigned short Vs[2 * 128 * 32];  // 16 KB
    const int t = threadIdx.x, wave = t >> 6, lane = t & 63;
    const int ln = lane & 15, quad = lane >> 4;
    // XCD swizzle: id = (b*4+kv) + 8*(g + 4*qb_local)
    const int id = blockIdx.x;
    const int pair = id & 7, b = pair >> 2, kv = pair & 3;
    const int rest = id >> 3, g4 = rest & 3, h = g4 * 4 + kv;
    const int qb = qb_base + (rest >> 2);
    const int q0 = qb * 64;

    const unsigned short* Kbase = Kb + (size_t)(b * NKV + kv) * NSEQ * 128;
    const unsigned short* Vbase = Vt + (size_t)(b * NKV + kv) * 128 * NSEQ;
    const float* bbase = bias2 + b * NSEQ;

    // Q fragments (B-operand), 2 row-tiles x 4 K-chunks
    const unsigned short* Qp =
        Qb + ((size_t)(b * NH + h) * NSEQ + q0 + wave * 32 + ln) * 128;
    short8 qf[2][4];
#pragma unroll
    for (int rt = 0; rt < 2; rt++)
#pragma unroll
        for (int kc = 0; kc < 4; kc++)
            qf[rt][kc] = *(const short8*)(Qp + rt * 16 * 128 + kc * 32 + quad * 8);

    // loop-invariant swizzled LDS base pointers
    const char* kp[4];
#pragma unroll
    for (int kc = 0; kc < 4; kc++)
        kp[kc] = (const char*)Ks + ln * 256 + (((kc * 4 + quad) ^ (ln & 7)) * 16);
    const char* vpp = (const char*)Vs + ln * 64 + ((quad ^ ((ln ^ (ln >> 2)) & 3)) * 16);

    floatx4 Oacc[2][8];
#pragma unroll
    for (int rt = 0; rt < 2; rt++)
#pragma unroll
        for (int d = 0; d < 8; d++) Oacc[rt][d] = fzero4();
    floatx4 Lacc[2];
    Lacc[0] = fzero4(); Lacc[1] = fzero4();

    short8 ones8;
#pragma unroll
    for (int i = 0; i < 8; i++) ones8[i] = (short)0x3F80;  // bf16 1.0

    auto stage = [&](int ktn, int buf) {
        // K tile 32x128 (8KB): 4 chunks/thread; swizzle on source addr
#pragma unroll
        for (int i = 0; i < 4; i++) {
            int c = i * 128 + t, r = c >> 4, c8 = c & 15;
            __builtin_amdgcn_global_load_lds(
                (gptr_t)(Kbase + (size_t)(ktn + r) * 128 + ((c8 ^ (r & 7)) * 8)),
                (lptr_t)(Ks + buf * 4096 + c * 8), 16, 0, 0);
        }
        // V tile 128x32 (8KB): swizzle f(dr) = (dr ^ dr>>2) & 3
#pragma unroll
        for (int i = 0; i < 4; i++) {
            int c = i * 128 + t, dr = c >> 2, c8 = c & 3;
            int f = (dr ^ (dr >> 2)) & 3;
            __builtin_amdgcn_global_load_lds(
                (gptr_t)(Vbase + (size_t)dr * NSEQ + ktn + ((c8 ^ f) * 8)),
                (lptr_t)(Vs + buf * 4096 + c * 8), 16, 0, 0);
        }
    };

    stage(0, 0);
    __syncthreads();

#pragma unroll 1
    for (int it2 = 0; it2 < NSEQ / 64; ++it2) {
#pragma unroll
        for (int half = 0; half < 2; ++half) {
            const int kt = (it2 * 2 + half) * 32;
            const int ktn = (kt + 32) & (NSEQ - 1);  // wrap: harmless reload
            stage(ktn, half ^ 1);
            const int off = half * 8192;  // byte offset of current buffer

            // S^T = mfma(A=K, B=Q): D[key=quad*4+g][q=ln]; C-init = bias
            floatx4 sacc[2][2];
#pragma unroll
            for (int nj = 0; nj < 2; nj++) {
                floatx4 bv = *(const floatx4*)(bbase + kt + nj * 16 + quad * 4);
                sacc[0][nj] = bv;
                sacc[1][nj] = bv;
            }
            __builtin_amdgcn_s_setprio(1);
#pragma unroll
            for (int kc = 0; kc < 4; kc++) {
                short8 kfv[2];
#pragma unroll
                for (int nj = 0; nj < 2; nj++)
                    kfv[nj] = *(const short8*)(kp[kc] + off + nj * 4096);
#pragma unroll
                for (int rt = 0; rt < 2; rt++)
#pragma unroll
                    for (int nj = 0; nj < 2; nj++)
                        sacc[rt][nj] = __builtin_amdgcn_mfma_f32_16x16x32_bf16(
                            kfv[nj], qf[rt][kc], sacc[rt][nj], 0, 0, 0);
            }
            __builtin_amdgcn_s_setprio(0);

            // p = exp2(s); pack keys k=quad*8+e*4+g (1 v_perm / pair)
            short8 pf[2];
#pragma unroll
            for (int rt = 0; rt < 2; rt++) {
                union { short8 s; unsigned int w[4]; } pu;
#pragma unroll
                for (int e = 0; e < 2; e++) {
                    float e0 = EXP2F(sacc[rt][e][0]);
                    float e1 = EXP2F(sacc[rt][e][1]);
                    float e2 = EXP2F(sacc[rt][e][2]);
                    float e3 = EXP2F(sacc[rt][e][3]);
                    pu.w[e * 2 + 0] = pk2bf_trunc(e0, e1);
                    pu.w[e * 2 + 1] = pk2bf_trunc(e2, e3);
                }
                pf[rt] = pu.s;
            }

            // row sums via ones-MFMA; O^T += mfma(A=V^T, B=P): D[d][q=ln]
            __builtin_amdgcn_s_setprio(1);
#pragma unroll
            for (int rt = 0; rt < 2; rt++)
                Lacc[rt] = __builtin_amdgcn_mfma_f32_16x16x32_bf16(
                    ones8, pf[rt], Lacc[rt], 0, 0, 0);
#pragma unroll
            for (int dt = 0; dt < 8; dt++) {
                short8 vf = *(const short8*)(vpp + off + dt * 1024);
#pragma unroll
                for (int rt = 0; rt < 2; rt++)
                    Oacc[rt][dt] = __builtin_amdgcn_mfma_f32_16x16x32_bf16(
                        vf, pf[rt], Oacc[rt][dt], 0, 0, 0);
            }
            __builtin_amdgcn_s_setprio(0);
            __syncthreads();  // next-tile DMA drained; swap buffers
        }
    }

    // epilogue: lane holds q=ln (uniform l), d=dt*16+quad*4+g -> b64 stores
#pragma unroll
    for (int rt = 0; rt < 2; rt++) {
        float inv = 1.f / Lacc[rt][0];
        int row = q0 + wave * 32 + rt * 16 + ln;
        unsigned short* outp = Ab + (size_t)(b * NSEQ + row) * 2048 + h * 128;
#pragma unroll
        for (int dt = 0; dt < 8; dt++) {
            short4v o4;
#pragma unroll
            for (int g = 0; g < 4; g++) o4[g] = (short)f2bf(Oacc[rt][dt][g] * inv);
            *(short4v*)(outp + dt * 16 + quad * 4) = o4;
        }
    }
}

extern "C" void kernel_launch(void* const* d_in, const int* in_sizes, int n_in,
                              void* d_out, int out_size, void* d_ws, size_t ws_size,
                              hipStream_t stream) {
    const float* x    = (const float*)d_in[0];
    const float* cosb = (const float*)d_in[1];
    const float* sinb = (const float*)d_in[2];
    const float* mask = (const float*)d_in[3];
    const float* Wq   = (const float*)d_in[4];
    const float* Wkv  = (const float*)d_in[5];
    const float* Wo   = (const float*)d_in[6];
    const float* bo   = (const float*)d_in[7];
    float* out = (float*)d_out;

    char* ws = (char*)d_ws;
    unsigned short* xb  = (unsigned short*)ws; ws += (size_t)4096 * 2048 * 2;
    unsigned short* W1T = (unsigned short*)ws; ws += (size_t)3072 * 2048 * 2;
    unsigned short* WoT = (unsigned short*)ws; ws += (size_t)2048 * 2048 * 2;
    unsigned short* Qb  = (unsigned short*)ws; ws += (size_t)2 * 16 * 2048 * 128 * 2;
    unsigned short* Kb  = (unsigned short*)ws; ws += (size_t)2 * 4 * 2048 * 128 * 2;
    unsigned short* Vt  = (unsigned short*)ws; ws += (size_t)2 * 4 * 2048 * 128 * 2;
    unsigned short* Ab  = (unsigned short*)ws; ws += (size_t)2 * 2048 * 2048 * 2;
    float* bias2 = (float*)ws;                 ws += (size_t)NB * NSEQ * 4;

    prep_k<<<18436, 256, 0, stream>>>(x, Wq, Wkv, Wo, mask, xb, W1T, WoT, bias2);
    gemm_qkv_rope<<<768, 256, 0, stream>>>(xb, W1T, cosb, sinb, Qb, Kb, Vt);
    attn_k<<<512, 128, 0, stream>>>(Qb, Kb, Vt, bias2, Ab, 0);
    attn_k<<<512, 128, 0, stream>>>(Qb, Kb, Vt, bias2, Ab, 16);
    gemm_bt<<<512, 256, 0, stream>>>(Ab, WoT, out, bo, 4096, 2048, 2048);
}

// Round 8
// 309.480 us; speedup vs baseline: 1.1656x; 1.1656x over previous
//
#include <hip/hip_runtime.h>
#include <hip/hip_bf16.h>
#include <cstddef>

// Problem constants (B=2, N=2048, D=2048, H=16, HKV=4, HD=128, G=4)
#define NB    2
#define NSEQ  2048
#define DMODEL 2048
#define NH    16
#define NKV   4
#define HDIM  128

typedef __attribute__((ext_vector_type(8))) short short8;
typedef __attribute__((ext_vector_type(4))) short short4v;
typedef __attribute__((ext_vector_type(4))) float floatx4;
typedef const __attribute__((address_space(1))) void* gptr_t;
typedef __attribute__((address_space(3))) void* lptr_t;

#if __has_builtin(__builtin_amdgcn_exp2f)
#define EXP2F(x) __builtin_amdgcn_exp2f(x)
#else
#define EXP2F(x) __expf((x) * 0.6931471805599453f)
#endif

__device__ inline unsigned short f2bf(float f) {
    // RTNE f32 -> bf16
    unsigned int u = __float_as_uint(f);
    u += 0x7fffu + ((u >> 16) & 1u);
    return (unsigned short)(u >> 16);
}

// pack two f32 -> two bf16 (truncating) in ONE v_perm_b32
__device__ inline unsigned int pk2bf_trunc(float a, float b) {
    return __builtin_amdgcn_perm(__float_as_uint(b), __float_as_uint(a), 0x07060302u);
}

__device__ inline floatx4 fzero4() {
    floatx4 v; v[0] = 0.f; v[1] = 0.f; v[2] = 0.f; v[3] = 0.f; return v;
}

// ---- merged prep: x cast, Wq/Wkv/Wo transpose+cast, mask->bias2 -----------
__global__ void prep_k(const float* __restrict__ x, const float* __restrict__ Wq,
                       const float* __restrict__ Wkv, const float* __restrict__ Wo,
                       const float* __restrict__ mask,
                       unsigned short* __restrict__ xb,
                       unsigned short* __restrict__ W1T,
                       unsigned short* __restrict__ WoT,
                       float* __restrict__ bias2) {
    __shared__ float tile[32][33];
    const int bid = blockIdx.x, t = threadIdx.x;
    if (bid < 8192) {  // cast x: 8192 blocks x 256 thr x float4
        int i = bid * 256 + t;
        float4 v = ((const float4*)x)[i];
        ushort4 o;
        o.x = f2bf(v.x); o.y = f2bf(v.y); o.z = f2bf(v.z); o.w = f2bf(v.w);
        ((ushort4*)xb)[i] = o;
        return;
    }
    if (bid >= 18432) {  // bias2 = (1-mask) * -1e9*log2e : 4 blocks
        int i = (bid - 18432) * 1024 + t * 4;
        float4 m = *(const float4*)(mask + i);
        const float c = -1.4426950408889634e9f;
        float4 o;
        o.x = (1.f - m.x) * c; o.y = (1.f - m.y) * c;
        o.z = (1.f - m.z) * c; o.w = (1.f - m.w) * c;
        *(float4*)(bias2 + i) = o;
        return;
    }
    // transposes (LDS 32x32 tiles, 32x8 thread layout)
    const float* W; unsigned short* Wt; int N, local;
    if (bid < 12288)      { W = Wq;  Wt = W1T;                       N = 2048; local = bid - 8192; }
    else if (bid < 14336) { W = Wkv; Wt = W1T + (size_t)2048 * 2048; N = 1024; local = bid - 12288; }
    else                  { W = Wo;  Wt = WoT;                       N = 2048; local = bid - 14336; }
    const int K = 2048;
    int nt = N >> 5;
    int bx = local % nt, by = local / nt;
    int n0 = bx * 32, k0 = by * 32, tx = t & 31, ty = t >> 5;
#pragma unroll
    for (int i = 0; i < 4; i++)
        tile[ty + i * 8][tx] = W[(size_t)(k0 + ty + i * 8) * N + n0 + tx];
    __syncthreads();
#pragma unroll
    for (int i = 0; i < 4; i++)
        Wt[(size_t)(n0 + ty + i * 8) * K + k0 + tx] = f2bf(tile[tx][ty + i * 8]);
}

// ---------------- m97-style bf16 GEMM, B-transposed input ------------------
// 1D grid + T1 XCD-chunked swizzle (nwg%8==0 -> bijective): each XCD gets a
// contiguous wgid chunk so neighbor tiles (sharing A/B panels) hit its L2.
__global__ __launch_bounds__(256, 3) void gemm_bt(
    const unsigned short* __restrict__ A,
    const unsigned short* __restrict__ Bt,
    float* __restrict__ C,
    const float* __restrict__ bias,
    int M, int N, int K) {
    __shared__ __align__(16) unsigned short As[128 * 32];
    __shared__ __align__(16) unsigned short Bs[128 * 32];
    const int t = threadIdx.x;
    const int chunk = gridDim.x >> 3;
    const int wgid = (blockIdx.x & 7) * chunk + (blockIdx.x >> 3);
    const int nx = N >> 7;
    const int m0 = (wgid / nx) * 128, n0 = (wgid % nx) * 128;
    const int lane = t & 63, wave = t >> 6;
    const int ln = lane & 15, quad = lane >> 4;
    const int wm = (wave >> 1) * 64, wn = (wave & 1) * 64;
    floatx4 acc[4][4];
#pragma unroll
    for (int r = 0; r < 4; r++)
#pragma unroll
        for (int c = 0; c < 4; c++) acc[r][c] = fzero4();

    const int r0 = t >> 2, c0 = (t & 3) * 8;
    const int r1 = (t + 256) >> 2, c1 = ((t + 256) & 3) * 8;

    for (int kt = 0; kt < K; kt += 32) {
        const unsigned short* ga0 = A + (size_t)(m0 + r0) * K + kt + c0;
        const unsigned short* ga1 = A + (size_t)(m0 + r1) * K + kt + c1;
        const unsigned short* gb0 = Bt + (size_t)(n0 + r0) * K + kt + c0;
        const unsigned short* gb1 = Bt + (size_t)(n0 + r1) * K + kt + c1;
        __builtin_amdgcn_global_load_lds((gptr_t)ga0, (lptr_t)(As + t * 8), 16, 0, 0);
        __builtin_amdgcn_global_load_lds((gptr_t)ga1, (lptr_t)(As + (t + 256) * 8), 16, 0, 0);
        __builtin_amdgcn_global_load_lds((gptr_t)gb0, (lptr_t)(Bs + t * 8), 16, 0, 0);
        __builtin_amdgcn_global_load_lds((gptr_t)gb1, (lptr_t)(Bs + (t + 256) * 8), 16, 0, 0);
        __syncthreads();
        short8 af[4], bfr[4];
#pragma unroll
        for (int r = 0; r < 4; r++)
            af[r] = *(const short8*)(As + (wm + r * 16 + ln) * 32 + quad * 8);
#pragma unroll
        for (int c = 0; c < 4; c++)
            bfr[c] = *(const short8*)(Bs + (wn + c * 16 + ln) * 32 + quad * 8);
#pragma unroll
        for (int r = 0; r < 4; r++)
#pragma unroll
            for (int c = 0; c < 4; c++)
                acc[r][c] = __builtin_amdgcn_mfma_f32_16x16x32_bf16(af[r], bfr[c], acc[r][c], 0, 0, 0);
        __syncthreads();
    }
#pragma unroll
    for (int r = 0; r < 4; r++) {
        int mb = m0 + wm + r * 16 + quad * 4;
#pragma unroll
        for (int c = 0; c < 4; c++) {
            int col = n0 + wn + c * 16 + ln;
            float bv = bias ? bias[col] : 0.f;
#pragma unroll
            for (int g = 0; g < 4; g++)
                C[(size_t)(mb + g) * N + col] = acc[r][c][g] + bv;
        }
    }
}

// ------- fused projection GEMM + RoPE + Q/K/V layout (bf16 outputs) --------
// 1D grid (768 = 8 XCD x 96) + T1 chunked swizzle, same decode as gemm_bt.
__global__ __launch_bounds__(256, 3) void gemm_qkv_rope(
    const unsigned short* __restrict__ A,    // xb (4096 x 2048)
    const unsigned short* __restrict__ Bt,   // W1T (3072 x 2048)
    const float* __restrict__ cosb,          // (N,64)
    const float* __restrict__ sinb,          // (N,64)
    unsigned short* __restrict__ Qb,
    unsigned short* __restrict__ Kb,
    unsigned short* __restrict__ Vt) {
    const int K = DMODEL;
    __shared__ __align__(16) unsigned short As[128 * 32];
    __shared__ __align__(16) unsigned short Bs[128 * 32];
    __shared__ __align__(16) unsigned short Vx[128 * 136];  // v-transpose tile
    const int t = threadIdx.x;
    const int wgid = (blockIdx.x & 7) * 96 + (blockIdx.x >> 3);
    const int m0 = (wgid / 24) * 128, n0 = (wgid % 24) * 128;
    const int lane = t & 63, wave = t >> 6;
    const int ln = lane & 15, quad = lane >> 4;
    const int wm = (wave >> 1) * 64, bq = (wave & 1) * 32;
    floatx4 acc[4][4];
#pragma unroll
    for (int r = 0; r < 4; r++)
#pragma unroll
        for (int c = 0; c < 4; c++) acc[r][c] = fzero4();

    const int r0 = t >> 2, c0 = (t & 3) * 8;
    const int r1 = (t + 256) >> 2, c1 = ((t + 256) & 3) * 8;

    for (int kt = 0; kt < K; kt += 32) {
        const unsigned short* ga0 = A + (size_t)(m0 + r0) * K + kt + c0;
        const unsigned short* ga1 = A + (size_t)(m0 + r1) * K + kt + c1;
        const unsigned short* gb0 = Bt + (size_t)(n0 + r0) * K + kt + c0;
        const unsigned short* gb1 = Bt + (size_t)(n0 + r1) * K + kt + c1;
        __builtin_amdgcn_global_load_lds((gptr_t)ga0, (lptr_t)(As + t * 8), 16, 0, 0);
        __builtin_amdgcn_global_load_lds((gptr_t)ga1, (lptr_t)(As + (t + 256) * 8), 16, 0, 0);
        __builtin_amdgcn_global_load_lds((gptr_t)gb0, (lptr_t)(Bs + t * 8), 16, 0, 0);
        __builtin_amdgcn_global_load_lds((gptr_t)gb1, (lptr_t)(Bs + (t + 256) * 8), 16, 0, 0);
        __syncthreads();
        short8 af[4], bfr[4];
#pragma unroll
        for (int r = 0; r < 4; r++)
            af[r] = *(const short8*)(As + (wm + r * 16 + ln) * 32 + quad * 8);
#pragma unroll
        for (int c = 0; c < 4; c++)
            bfr[c] = *(const short8*)(
                Bs + (bq + (c & 1) * 16 + (c >> 1) * 64 + ln) * 32 + quad * 8);
#pragma unroll
        for (int r = 0; r < 4; r++)
#pragma unroll
            for (int c = 0; c < 4; c++)
                acc[r][c] = __builtin_amdgcn_mfma_f32_16x16x32_bf16(af[r], bfr[c], acc[r][c], 0, 0, 0);
        __syncthreads();
    }

    // ---------------- epilogue ----------------
    if (n0 < 2048) {
        const float qs = (float)(0.08838834764831845 * 1.4426950408889634);
        int h = n0 >> 7;
#pragma unroll
        for (int r = 0; r < 4; r++)
#pragma unroll
            for (int c = 0; c < 2; c++)
#pragma unroll
                for (int g = 0; g < 4; g++) {
                    int row = m0 + wm + r * 16 + quad * 4 + g;
                    int b = row >> 11, n = row & 2047;
                    int j = bq + c * 16 + ln;
                    float cv = cosb[n * 64 + j], sv = sinb[n * 64 + j];
                    float t1 = acc[r][c][g], t2 = acc[r][c + 2][g];
                    unsigned short* qp = Qb + ((size_t)(b * NH + h) * NSEQ + n) * 128;
                    qp[j]      = f2bf((t1 * cv + t2 * sv) * qs);
                    qp[j + 64] = f2bf((t2 * cv - t1 * sv) * qs);
                }
    } else if (n0 < 2560) {
        int hk = (n0 - 2048) >> 7;
#pragma unroll
        for (int r = 0; r < 4; r++)
#pragma unroll
            for (int c = 0; c < 2; c++)
#pragma unroll
                for (int g = 0; g < 4; g++) {
                    int row = m0 + wm + r * 16 + quad * 4 + g;
                    int b = row >> 11, n = row & 2047;
                    int j = bq + c * 16 + ln;
                    float cv = cosb[n * 64 + j], sv = sinb[n * 64 + j];
                    float t1 = acc[r][c][g], t2 = acc[r][c + 2][g];
                    unsigned short* kp = Kb + ((size_t)(b * NKV + hk) * NSEQ + n) * 128;
                    kp[j]      = f2bf(t1 * cv + t2 * sv);
                    kp[j + 64] = f2bf(t2 * cv - t1 * sv);
                }
    } else {
        int hk = (n0 - 2560) >> 7;
#pragma unroll
        for (int r = 0; r < 4; r++)
#pragma unroll
            for (int c = 0; c < 4; c++) {
                int d = bq + (c & 1) * 16 + (c >> 1) * 64 + ln;
                int s = wm + (r >> 1) * 32 + quad * 8 + (r & 1) * 4;
#pragma unroll
                for (int g = 0; g < 4; g++)
                    Vx[d * 136 + s + g] = f2bf(acc[r][c][g]);
            }
        __syncthreads();
        int b = m0 >> 11, nloc = m0 & 2047;
#pragma unroll
        for (int pass = 0; pass < 2; pass++) {
            int d = pass * 64 + (t >> 2), q4 = t & 3;
            unsigned short* vp =
                Vt + ((size_t)(b * NKV + hk) * 128 + d) * NSEQ + nloc + q4 * 32;
#pragma unroll
            for (int i = 0; i < 4; i++)
                *(short8*)(vp + i * 8) = *(const short8*)(Vx + d * 136 + q4 * 32 + i * 8);
        }
    }
}

// ---- flash attention (v11 = r6 v9 exactly: single 1024-block launch) ------
// r7 lesson quantified: this kernel's latency hiding is CROSS-BLOCK drift
// (m114) — 4 blocks/CU on one launch gives 4 independent barrier domains;
// splitting to 2 blocks/CU exposed the per-tile vmcnt drain (85 -> 163 us
// aggregate).  Body: 2 waves x 32 q-rows, bias-as-C-init, T5 setprio.
__global__ __launch_bounds__(128, 2) void attn_k(
    const unsigned short* __restrict__ Qb,   // (B,H,N,HD)
    const unsigned short* __restrict__ Kb,   // (B,HKV,N,HD)
    const unsigned short* __restrict__ Vt,   // (B,HKV,HD,N) permuted cols
    const float* __restrict__ bias2,         // (B,N) = (1-mask)*-1e9*log2e
    unsigned short* __restrict__ Ab) {       // (B,N,H*HD) bf16
    __shared__ __align__(16) unsigned short Ks[2 * 32 * 128];  // 16 KB
    __shared__ __align__(16) unsigned short Vs[2 * 128 * 32];  // 16 KB
    const int t = threadIdx.x, wave = t >> 6, lane = t & 63;
    const int ln = lane & 15, quad = lane >> 4;
    // XCD swizzle: id = (b*4+kv) + 8*(g + 4*qb)
    const int id = blockIdx.x;
    const int pair = id & 7, b = pair >> 2, kv = pair & 3;
    const int rest = id >> 3, g4 = rest & 3, h = g4 * 4 + kv, qb = rest >> 2;
    const int q0 = qb * 64;

    const unsigned short* Kbase = Kb + (size_t)(b * NKV + kv) * NSEQ * 128;
    const unsigned short* Vbase = Vt + (size_t)(b * NKV + kv) * 128 * NSEQ;
    const float* bbase = bias2 + b * NSEQ;

    // Q fragments (B-operand), 2 row-tiles x 4 K-chunks
    const unsigned short* Qp =
        Qb + ((size_t)(b * NH + h) * NSEQ + q0 + wave * 32 + ln) * 128;
    short8 qf[2][4];
#pragma unroll
    for (int rt = 0; rt < 2; rt++)
#pragma unroll
        for (int kc = 0; kc < 4; kc++)
            qf[rt][kc] = *(const short8*)(Qp + rt * 16 * 128 + kc * 32 + quad * 8);

    // loop-invariant swizzled LDS base pointers
    const char* kp[4];
#pragma unroll
    for (int kc = 0; kc < 4; kc++)
        kp[kc] = (const char*)Ks + ln * 256 + (((kc * 4 + quad) ^ (ln & 7)) * 16);
    const char* vpp = (const char*)Vs + ln * 64 + ((quad ^ ((ln ^ (ln >> 2)) & 3)) * 16);

    floatx4 Oacc[2][8];
#pragma unroll
    for (int rt = 0; rt < 2; rt++)
#pragma unroll
        for (int d = 0; d < 8; d++) Oacc[rt][d] = fzero4();
    floatx4 Lacc[2];
    Lacc[0] = fzero4(); Lacc[1] = fzero4();

    short8 ones8;
#pragma unroll
    for (int i = 0; i < 8; i++) ones8[i] = (short)0x3F80;  // bf16 1.0

    auto stage = [&](int ktn, int buf) {
        // K tile 32x128 (8KB): 4 chunks/thread; swizzle on source addr
#pragma unroll
        for (int i = 0; i < 4; i++) {
            int c = i * 128 + t, r = c >> 4, c8 = c & 15;
            __builtin_amdgcn_global_load_lds(
                (gptr_t)(Kbase + (size_t)(ktn + r) * 128 + ((c8 ^ (r & 7)) * 8)),
                (lptr_t)(Ks + buf * 4096 + c * 8), 16, 0, 0);
        }
        // V tile 128x32 (8KB): swizzle f(dr) = (dr ^ dr>>2) & 3
#pragma unroll
        for (int i = 0; i < 4; i++) {
            int c = i * 128 + t, dr = c >> 2, c8 = c & 3;
            int f = (dr ^ (dr >> 2)) & 3;
            __builtin_amdgcn_global_load_lds(
                (gptr_t)(Vbase + (size_t)dr * NSEQ + ktn + ((c8 ^ f) * 8)),
                (lptr_t)(Vs + buf * 4096 + c * 8), 16, 0, 0);
        }
    };

    stage(0, 0);
    __syncthreads();

#pragma unroll 1
    for (int it2 = 0; it2 < NSEQ / 64; ++it2) {
#pragma unroll
        for (int half = 0; half < 2; ++half) {
            const int kt = (it2 * 2 + half) * 32;
            const int ktn = (kt + 32) & (NSEQ - 1);  // wrap: harmless reload
            stage(ktn, half ^ 1);
            const int off = half * 8192;  // byte offset of current buffer

            // S^T = mfma(A=K, B=Q): D[key=quad*4+g][q=ln]; C-init = bias
            floatx4 sacc[2][2];
#pragma unroll
            for (int nj = 0; nj < 2; nj++) {
                floatx4 bv = *(const floatx4*)(bbase + kt + nj * 16 + quad * 4);
                sacc[0][nj] = bv;
                sacc[1][nj] = bv;
            }
            __builtin_amdgcn_s_setprio(1);
#pragma unroll
            for (int kc = 0; kc < 4; kc++) {
                short8 kfv[2];
#pragma unroll
                for (int nj = 0; nj < 2; nj++)
                    kfv[nj] = *(const short8*)(kp[kc] + off + nj * 4096);
#pragma unroll
                for (int rt = 0; rt < 2; rt++)
#pragma unroll
                    for (int nj = 0; nj < 2; nj++)
                        sacc[rt][nj] = __builtin_amdgcn_mfma_f32_16x16x32_bf16(
                            kfv[nj], qf[rt][kc], sacc[rt][nj], 0, 0, 0);
            }
            __builtin_amdgcn_s_setprio(0);

            // p = exp2(s); pack keys k=quad*8+e*4+g (1 v_perm / pair)
            short8 pf[2];
#pragma unroll
            for (int rt = 0; rt < 2; rt++) {
                union { short8 s; unsigned int w[4]; } pu;
#pragma unroll
                for (int e = 0; e < 2; e++) {
                    float e0 = EXP2F(sacc[rt][e][0]);
                    float e1 = EXP2F(sacc[rt][e][1]);
                    float e2 = EXP2F(sacc[rt][e][2]);
                    float e3 = EXP2F(sacc[rt][e][3]);
                    pu.w[e * 2 + 0] = pk2bf_trunc(e0, e1);
                    pu.w[e * 2 + 1] = pk2bf_trunc(e2, e3);
                }
                pf[rt] = pu.s;
            }

            // row sums via ones-MFMA; O^T += mfma(A=V^T, B=P): D[d][q=ln]
            __builtin_amdgcn_s_setprio(1);
#pragma unroll
            for (int rt = 0; rt < 2; rt++)
                Lacc[rt] = __builtin_amdgcn_mfma_f32_16x16x32_bf16(
                    ones8, pf[rt], Lacc[rt], 0, 0, 0);
#pragma unroll
            for (int dt = 0; dt < 8; dt++) {
                short8 vf = *(const short8*)(vpp + off + dt * 1024);
#pragma unroll
                for (int rt = 0; rt < 2; rt++)
                    Oacc[rt][dt] = __builtin_amdgcn_mfma_f32_16x16x32_bf16(
                        vf, pf[rt], Oacc[rt][dt], 0, 0, 0);
            }
            __builtin_amdgcn_s_setprio(0);
            __syncthreads();  // next-tile DMA drained; swap buffers
        }
    }

    // epilogue: lane holds q=ln (uniform l), d=dt*16+quad*4+g -> b64 stores
#pragma unroll
    for (int rt = 0; rt < 2; rt++) {
        float inv = 1.f / Lacc[rt][0];
        int row = q0 + wave * 32 + rt * 16 + ln;
        unsigned short* outp = Ab + (size_t)(b * NSEQ + row) * 2048 + h * 128;
#pragma unroll
        for (int dt = 0; dt < 8; dt++) {
            short4v o4;
#pragma unroll
            for (int g = 0; g < 4; g++) o4[g] = (short)f2bf(Oacc[rt][dt][g] * inv);
            *(short4v*)(outp + dt * 16 + quad * 4) = o4;
        }
    }
}

extern "C" void kernel_launch(void* const* d_in, const int* in_sizes, int n_in,
                              void* d_out, int out_size, void* d_ws, size_t ws_size,
                              hipStream_t stream) {
    const float* x    = (const float*)d_in[0];
    const float* cosb = (const float*)d_in[1];
    const float* sinb = (const float*)d_in[2];
    const float* mask = (const float*)d_in[3];
    const float* Wq   = (const float*)d_in[4];
    const float* Wkv  = (const float*)d_in[5];
    const float* Wo   = (const float*)d_in[6];
    const float* bo   = (const float*)d_in[7];
    float* out = (float*)d_out;

    char* ws = (char*)d_ws;
    unsigned short* xb  = (unsigned short*)ws; ws += (size_t)4096 * 2048 * 2;
    unsigned short* W1T = (unsigned short*)ws; ws += (size_t)3072 * 2048 * 2;
    unsigned short* WoT = (unsigned short*)ws; ws += (size_t)2048 * 2048 * 2;
    unsigned short* Qb  = (unsigned short*)ws; ws += (size_t)2 * 16 * 2048 * 128 * 2;
    unsigned short* Kb  = (unsigned short*)ws; ws += (size_t)2 * 4 * 2048 * 128 * 2;
    unsigned short* Vt  = (unsigned short*)ws; ws += (size_t)2 * 4 * 2048 * 128 * 2;
    unsigned short* Ab  = (unsigned short*)ws; ws += (size_t)2 * 2048 * 2048 * 2;
    float* bias2 = (float*)ws;                 ws += (size_t)NB * NSEQ * 4;

    prep_k<<<18436, 256, 0, stream>>>(x, Wq, Wkv, Wo, mask, xb, W1T, WoT, bias2);
    gemm_qkv_rope<<<768, 256, 0, stream>>>(xb, W1T, cosb, sinb, Qb, Kb, Vt);
    attn_k<<<1024, 128, 0, stream>>>(Qb, Kb, Vt, bias2, Ab);
    gemm_bt<<<512, 256, 0, stream>>>(Ab, WoT, out, bo, 4096, 2048, 2048);
}

// Round 9
// 300.746 us; speedup vs baseline: 1.1995x; 1.0290x over previous
//
#include <hip/hip_runtime.h>
#include <hip/hip_bf16.h>
#include <cstddef>

// Problem constants (B=2, N=2048, D=2048, H=16, HKV=4, HD=128, G=4)
#define NB    2
#define NSEQ  2048
#define DMODEL 2048
#define NH    16
#define NKV   4
#define HDIM  128

typedef __attribute__((ext_vector_type(8))) short short8;
typedef __attribute__((ext_vector_type(4))) short short4v;
typedef __attribute__((ext_vector_type(4))) float floatx4;
typedef const __attribute__((address_space(1))) void* gptr_t;
typedef __attribute__((address_space(3))) void* lptr_t;

#if __has_builtin(__builtin_amdgcn_exp2f)
#define EXP2F(x) __builtin_amdgcn_exp2f(x)
#else
#define EXP2F(x) __expf((x) * 0.6931471805599453f)
#endif

__device__ inline unsigned short f2bf(float f) {
    // RTNE f32 -> bf16
    unsigned int u = __float_as_uint(f);
    u += 0x7fffu + ((u >> 16) & 1u);
    return (unsigned short)(u >> 16);
}

// pack two f32 -> two bf16 (truncating) in ONE v_perm_b32
__device__ inline unsigned int pk2bf_trunc(float a, float b) {
    return __builtin_amdgcn_perm(__float_as_uint(b), __float_as_uint(a), 0x07060302u);
}

__device__ inline floatx4 fzero4() {
    floatx4 v; v[0] = 0.f; v[1] = 0.f; v[2] = 0.f; v[3] = 0.f; return v;
}

// ---- merged prep: x cast, Wq/Wkv/Wo transpose+cast, mask->bias2 -----------
__global__ void prep_k(const float* __restrict__ x, const float* __restrict__ Wq,
                       const float* __restrict__ Wkv, const float* __restrict__ Wo,
                       const float* __restrict__ mask,
                       unsigned short* __restrict__ xb,
                       unsigned short* __restrict__ W1T,
                       unsigned short* __restrict__ WoT,
                       float* __restrict__ bias2) {
    __shared__ float tile[32][33];
    const int bid = blockIdx.x, t = threadIdx.x;
    if (bid < 8192) {  // cast x: 8192 blocks x 256 thr x float4
        int i = bid * 256 + t;
        float4 v = ((const float4*)x)[i];
        ushort4 o;
        o.x = f2bf(v.x); o.y = f2bf(v.y); o.z = f2bf(v.z); o.w = f2bf(v.w);
        ((ushort4*)xb)[i] = o;
        return;
    }
    if (bid >= 18432) {  // bias2 = (1-mask) * -1e9*log2e : 4 blocks
        int i = (bid - 18432) * 1024 + t * 4;
        float4 m = *(const float4*)(mask + i);
        const float c = -1.4426950408889634e9f;
        float4 o;
        o.x = (1.f - m.x) * c; o.y = (1.f - m.y) * c;
        o.z = (1.f - m.z) * c; o.w = (1.f - m.w) * c;
        *(float4*)(bias2 + i) = o;
        return;
    }
    // transposes (LDS 32x32 tiles, 32x8 thread layout)
    const float* W; unsigned short* Wt; int N, local;
    if (bid < 12288)      { W = Wq;  Wt = W1T;                       N = 2048; local = bid - 8192; }
    else if (bid < 14336) { W = Wkv; Wt = W1T + (size_t)2048 * 2048; N = 1024; local = bid - 12288; }
    else                  { W = Wo;  Wt = WoT;                       N = 2048; local = bid - 14336; }
    const int K = 2048;
    int nt = N >> 5;
    int bx = local % nt, by = local / nt;
    int n0 = bx * 32, k0 = by * 32, tx = t & 31, ty = t >> 5;
#pragma unroll
    for (int i = 0; i < 4; i++)
        tile[ty + i * 8][tx] = W[(size_t)(k0 + ty + i * 8) * N + n0 + tx];
    __syncthreads();
#pragma unroll
    for (int i = 0; i < 4; i++)
        Wt[(size_t)(n0 + ty + i * 8) * K + k0 + tx] = f2bf(tile[tx][ty + i * 8]);
}

// ---------------- m97-style bf16 GEMM, BK=64, B-transposed input -----------
// BK=32->64 halves the barrier count (K=2048: 128 -> 64 full-drain barriers,
// the dominant per-iteration overhead at short K).  [128][64] rows are 128B
// stride = 16-way bank conflict (G4/m201) -> both-sides XOR swizzle lifted
// from attn_k's proven stage pattern: source chunk c8^(r&7) pre-swizzled,
// ds_read chunk (kc*4+quad)^(ln&7) (row&7==ln&7 for all fragment rows).
// Fragments re-read per kc pass (2 passes) so VGPR stays ~164 -> 3 blk/CU.
__global__ __launch_bounds__(256, 3) void gemm_bt(
    const unsigned short* __restrict__ A,
    const unsigned short* __restrict__ Bt,
    float* __restrict__ C,
    const float* __restrict__ bias,
    int M, int N, int K) {
    __shared__ __align__(16) unsigned short As[128 * 64];
    __shared__ __align__(16) unsigned short Bs[128 * 64];
    const int t = threadIdx.x;
    const int chunk = gridDim.x >> 3;
    const int wgid = (blockIdx.x & 7) * chunk + (blockIdx.x >> 3);
    const int nx = N >> 7;
    const int m0 = (wgid / nx) * 128, n0 = (wgid % nx) * 128;
    const int lane = t & 63, wave = t >> 6;
    const int ln = lane & 15, quad = lane >> 4;
    const int wm = (wave >> 1) * 64, wn = (wave & 1) * 64;
    floatx4 acc[4][4];
#pragma unroll
    for (int r = 0; r < 4; r++)
#pragma unroll
        for (int c = 0; c < 4; c++) acc[r][c] = fzero4();

    // swizzled in-row chunk offsets (elements) for the 2 kc passes
    int xsw[2];
#pragma unroll
    for (int kc = 0; kc < 2; kc++)
        xsw[kc] = (((kc << 2) + quad) ^ (ln & 7)) * 8;

    for (int kt = 0; kt < K; kt += 64) {
#pragma unroll
        for (int i = 0; i < 4; i++) {
            int c = i * 256 + t, r = c >> 3, c8 = c & 7;
            int scol = kt + ((c8 ^ (r & 7)) * 8);
            __builtin_amdgcn_global_load_lds(
                (gptr_t)(A + (size_t)(m0 + r) * K + scol),
                (lptr_t)(As + c * 8), 16, 0, 0);
            __builtin_amdgcn_global_load_lds(
                (gptr_t)(Bt + (size_t)(n0 + r) * K + scol),
                (lptr_t)(Bs + c * 8), 16, 0, 0);
        }
        __syncthreads();
#pragma unroll
        for (int kc = 0; kc < 2; kc++) {
            short8 af[4], bfr[4];
#pragma unroll
            for (int r = 0; r < 4; r++)
                af[r] = *(const short8*)(As + (wm + r * 16 + ln) * 64 + xsw[kc]);
#pragma unroll
            for (int c = 0; c < 4; c++)
                bfr[c] = *(const short8*)(Bs + (wn + c * 16 + ln) * 64 + xsw[kc]);
#pragma unroll
            for (int r = 0; r < 4; r++)
#pragma unroll
                for (int c = 0; c < 4; c++)
                    acc[r][c] = __builtin_amdgcn_mfma_f32_16x16x32_bf16(
                        af[r], bfr[c], acc[r][c], 0, 0, 0);
        }
        __syncthreads();
    }
#pragma unroll
    for (int r = 0; r < 4; r++) {
        int mb = m0 + wm + r * 16 + quad * 4;
#pragma unroll
        for (int c = 0; c < 4; c++) {
            int col = n0 + wn + c * 16 + ln;
            float bv = bias ? bias[col] : 0.f;
#pragma unroll
            for (int g = 0; g < 4; g++)
                C[(size_t)(mb + g) * N + col] = acc[r][c][g] + bv;
        }
    }
}

// ------- fused projection GEMM + RoPE + Q/K/V layout (bf16 outputs) --------
// Same BK=64 + swizzle main loop as gemm_bt.  Vx (epilogue-only, 34.8KB) is
// aliased onto As/Bs (dead after the K-loop's final barrier) -> LDS 34.8KB
// total (was 50.8KB).
__global__ __launch_bounds__(256, 3) void gemm_qkv_rope(
    const unsigned short* __restrict__ A,    // xb (4096 x 2048)
    const unsigned short* __restrict__ Bt,   // W1T (3072 x 2048)
    const float* __restrict__ cosb,          // (N,64)
    const float* __restrict__ sinb,          // (N,64)
    unsigned short* __restrict__ Qb,
    unsigned short* __restrict__ Kb,
    unsigned short* __restrict__ Vt) {
    const int K = DMODEL;
    __shared__ __align__(16) unsigned char smem[128 * 136 * 2];  // 34816 B
    unsigned short* As = (unsigned short*)smem;            // [128*64]
    unsigned short* Bs = (unsigned short*)(smem + 16384);  // [128*64]
    unsigned short* Vx = (unsigned short*)smem;            // [128*136] epi
    const int t = threadIdx.x;
    const int wgid = (blockIdx.x & 7) * 96 + (blockIdx.x >> 3);
    const int m0 = (wgid / 24) * 128, n0 = (wgid % 24) * 128;
    const int lane = t & 63, wave = t >> 6;
    const int ln = lane & 15, quad = lane >> 4;
    const int wm = (wave >> 1) * 64, bq = (wave & 1) * 32;
    floatx4 acc[4][4];
#pragma unroll
    for (int r = 0; r < 4; r++)
#pragma unroll
        for (int c = 0; c < 4; c++) acc[r][c] = fzero4();

    int xsw[2];
#pragma unroll
    for (int kc = 0; kc < 2; kc++)
        xsw[kc] = (((kc << 2) + quad) ^ (ln & 7)) * 8;

    for (int kt = 0; kt < K; kt += 64) {
#pragma unroll
        for (int i = 0; i < 4; i++) {
            int c = i * 256 + t, r = c >> 3, c8 = c & 7;
            int scol = kt + ((c8 ^ (r & 7)) * 8);
            __builtin_amdgcn_global_load_lds(
                (gptr_t)(A + (size_t)(m0 + r) * K + scol),
                (lptr_t)(As + c * 8), 16, 0, 0);
            __builtin_amdgcn_global_load_lds(
                (gptr_t)(Bt + (size_t)(n0 + r) * K + scol),
                (lptr_t)(Bs + c * 8), 16, 0, 0);
        }
        __syncthreads();
#pragma unroll
        for (int kc = 0; kc < 2; kc++) {
            short8 af[4], bfr[4];
#pragma unroll
            for (int r = 0; r < 4; r++)
                af[r] = *(const short8*)(As + (wm + r * 16 + ln) * 64 + xsw[kc]);
#pragma unroll
            for (int c = 0; c < 4; c++)
                bfr[c] = *(const short8*)(
                    Bs + (bq + (c & 1) * 16 + (c >> 1) * 64 + ln) * 64 + xsw[kc]);
#pragma unroll
            for (int r = 0; r < 4; r++)
#pragma unroll
                for (int c = 0; c < 4; c++)
                    acc[r][c] = __builtin_amdgcn_mfma_f32_16x16x32_bf16(
                        af[r], bfr[c], acc[r][c], 0, 0, 0);
        }
        __syncthreads();
    }

    // ---------------- epilogue ----------------
    if (n0 < 2048) {
        const float qs = (float)(0.08838834764831845 * 1.4426950408889634);
        int h = n0 >> 7;
#pragma unroll
        for (int r = 0; r < 4; r++)
#pragma unroll
            for (int c = 0; c < 2; c++)
#pragma unroll
                for (int g = 0; g < 4; g++) {
                    int row = m0 + wm + r * 16 + quad * 4 + g;
                    int b = row >> 11, n = row & 2047;
                    int j = bq + c * 16 + ln;
                    float cv = cosb[n * 64 + j], sv = sinb[n * 64 + j];
                    float t1 = acc[r][c][g], t2 = acc[r][c + 2][g];
                    unsigned short* qp = Qb + ((size_t)(b * NH + h) * NSEQ + n) * 128;
                    qp[j]      = f2bf((t1 * cv + t2 * sv) * qs);
                    qp[j + 64] = f2bf((t2 * cv - t1 * sv) * qs);
                }
    } else if (n0 < 2560) {
        int hk = (n0 - 2048) >> 7;
#pragma unroll
        for (int r = 0; r < 4; r++)
#pragma unroll
            for (int c = 0; c < 2; c++)
#pragma unroll
                for (int g = 0; g < 4; g++) {
                    int row = m0 + wm + r * 16 + quad * 4 + g;
                    int b = row >> 11, n = row & 2047;
                    int j = bq + c * 16 + ln;
                    float cv = cosb[n * 64 + j], sv = sinb[n * 64 + j];
                    float t1 = acc[r][c][g], t2 = acc[r][c + 2][g];
                    unsigned short* kp = Kb + ((size_t)(b * NKV + hk) * NSEQ + n) * 128;
                    kp[j]      = f2bf(t1 * cv + t2 * sv);
                    kp[j + 64] = f2bf(t2 * cv - t1 * sv);
                }
    } else {
        int hk = (n0 - 2560) >> 7;
#pragma unroll
        for (int r = 0; r < 4; r++)
#pragma unroll
            for (int c = 0; c < 4; c++) {
                int d = bq + (c & 1) * 16 + (c >> 1) * 64 + ln;
                int s = wm + (r >> 1) * 32 + quad * 8 + (r & 1) * 4;
#pragma unroll
                for (int g = 0; g < 4; g++)
                    Vx[d * 136 + s + g] = f2bf(acc[r][c][g]);
            }
        __syncthreads();
        int b = m0 >> 11, nloc = m0 & 2047;
#pragma unroll
        for (int pass = 0; pass < 2; pass++) {
            int d = pass * 64 + (t >> 2), q4 = t & 3;
            unsigned short* vp =
                Vt + ((size_t)(b * NKV + hk) * 128 + d) * NSEQ + nloc + q4 * 32;
#pragma unroll
            for (int i = 0; i < 4; i++)
                *(short8*)(vp + i * 8) = *(const short8*)(Vx + d * 136 + q4 * 32 + i * 8);
        }
    }
}

// ---- flash attention (v11: single 1024-block launch; best measured 84.5us)
// 2 waves x 32 q-rows, bias-as-C-init, T5 setprio; latency hiding via 4
// independent barrier domains/CU (r7 quantified: 2 domains/CU -> 2x time).
__global__ __launch_bounds__(128, 2) void attn_k(
    const unsigned short* __restrict__ Qb,   // (B,H,N,HD)
    const unsigned short* __restrict__ Kb,   // (B,HKV,N,HD)
    const unsigned short* __restrict__ Vt,   // (B,HKV,HD,N) permuted cols
    const float* __restrict__ bias2,         // (B,N) = (1-mask)*-1e9*log2e
    unsigned short* __restrict__ Ab) {       // (B,N,H*HD) bf16
    __shared__ __align__(16) unsigned short Ks[2 * 32 * 128];  // 16 KB
    __shared__ __align__(16) unsigned short Vs[2 * 128 * 32];  // 16 KB
    const int t = threadIdx.x, wave = t >> 6, lane = t & 63;
    const int ln = lane & 15, quad = lane >> 4;
    // XCD swizzle: id = (b*4+kv) + 8*(g + 4*qb)
    const int id = blockIdx.x;
    const int pair = id & 7, b = pair >> 2, kv = pair & 3;
    const int rest = id >> 3, g4 = rest & 3, h = g4 * 4 + kv, qb = rest >> 2;
    const int q0 = qb * 64;

    const unsigned short* Kbase = Kb + (size_t)(b * NKV + kv) * NSEQ * 128;
    const unsigned short* Vbase = Vt + (size_t)(b * NKV + kv) * 128 * NSEQ;
    const float* bbase = bias2 + b * NSEQ;

    // Q fragments (B-operand), 2 row-tiles x 4 K-chunks
    const unsigned short* Qp =
        Qb + ((size_t)(b * NH + h) * NSEQ + q0 + wave * 32 + ln) * 128;
    short8 qf[2][4];
#pragma unroll
    for (int rt = 0; rt < 2; rt++)
#pragma unroll
        for (int kc = 0; kc < 4; kc++)
            qf[rt][kc] = *(const short8*)(Qp + rt * 16 * 128 + kc * 32 + quad * 8);

    // loop-invariant swizzled LDS base pointers
    const char* kp[4];
#pragma unroll
    for (int kc = 0; kc < 4; kc++)
        kp[kc] = (const char*)Ks + ln * 256 + (((kc * 4 + quad) ^ (ln & 7)) * 16);
    const char* vpp = (const char*)Vs + ln * 64 + ((quad ^ ((ln ^ (ln >> 2)) & 3)) * 16);

    floatx4 Oacc[2][8];
#pragma unroll
    for (int rt = 0; rt < 2; rt++)
#pragma unroll
        for (int d = 0; d < 8; d++) Oacc[rt][d] = fzero4();
    floatx4 Lacc[2];
    Lacc[0] = fzero4(); Lacc[1] = fzero4();

    short8 ones8;
#pragma unroll
    for (int i = 0; i < 8; i++) ones8[i] = (short)0x3F80;  // bf16 1.0

    auto stage = [&](int ktn, int buf) {
        // K tile 32x128 (8KB): 4 chunks/thread; swizzle on source addr
#pragma unroll
        for (int i = 0; i < 4; i++) {
            int c = i * 128 + t, r = c >> 4, c8 = c & 15;
            __builtin_amdgcn_global_load_lds(
                (gptr_t)(Kbase + (size_t)(ktn + r) * 128 + ((c8 ^ (r & 7)) * 8)),
                (lptr_t)(Ks + buf * 4096 + c * 8), 16, 0, 0);
        }
        // V tile 128x32 (8KB): swizzle f(dr) = (dr ^ dr>>2) & 3
#pragma unroll
        for (int i = 0; i < 4; i++) {
            int c = i * 128 + t, dr = c >> 2, c8 = c & 3;
            int f = (dr ^ (dr >> 2)) & 3;
            __builtin_amdgcn_global_load_lds(
                (gptr_t)(Vbase + (size_t)dr * NSEQ + ktn + ((c8 ^ f) * 8)),
                (lptr_t)(Vs + buf * 4096 + c * 8), 16, 0, 0);
        }
    };

    stage(0, 0);
    __syncthreads();

#pragma unroll 1
    for (int it2 = 0; it2 < NSEQ / 64; ++it2) {
#pragma unroll
        for (int half = 0; half < 2; ++half) {
            const int kt = (it2 * 2 + half) * 32;
            const int ktn = (kt + 32) & (NSEQ - 1);  // wrap: harmless reload
            stage(ktn, half ^ 1);
            const int off = half * 8192;  // byte offset of current buffer

            // S^T = mfma(A=K, B=Q): D[key=quad*4+g][q=ln]; C-init = bias
            floatx4 sacc[2][2];
#pragma unroll
            for (int nj = 0; nj < 2; nj++) {
                floatx4 bv = *(const floatx4*)(bbase + kt + nj * 16 + quad * 4);
                sacc[0][nj] = bv;
                sacc[1][nj] = bv;
            }
            __builtin_amdgcn_s_setprio(1);
#pragma unroll
            for (int kc = 0; kc < 4; kc++) {
                short8 kfv[2];
#pragma unroll
                for (int nj = 0; nj < 2; nj++)
                    kfv[nj] = *(const short8*)(kp[kc] + off + nj * 4096);
#pragma unroll
                for (int rt = 0; rt < 2; rt++)
#pragma unroll
                    for (int nj = 0; nj < 2; nj++)
                        sacc[rt][nj] = __builtin_amdgcn_mfma_f32_16x16x32_bf16(
                            kfv[nj], qf[rt][kc], sacc[rt][nj], 0, 0, 0);
            }
            __builtin_amdgcn_s_setprio(0);

            // p = exp2(s); pack keys k=quad*8+e*4+g (1 v_perm / pair)
            short8 pf[2];
#pragma unroll
            for (int rt = 0; rt < 2; rt++) {
                union { short8 s; unsigned int w[4]; } pu;
#pragma unroll
                for (int e = 0; e < 2; e++) {
                    float e0 = EXP2F(sacc[rt][e][0]);
                    float e1 = EXP2F(sacc[rt][e][1]);
                    float e2 = EXP2F(sacc[rt][e][2]);
                    float e3 = EXP2F(sacc[rt][e][3]);
                    pu.w[e * 2 + 0] = pk2bf_trunc(e0, e1);
                    pu.w[e * 2 + 1] = pk2bf_trunc(e2, e3);
                }
                pf[rt] = pu.s;
            }

            // row sums via ones-MFMA; O^T += mfma(A=V^T, B=P): D[d][q=ln]
            __builtin_amdgcn_s_setprio(1);
#pragma unroll
            for (int rt = 0; rt < 2; rt++)
                Lacc[rt] = __builtin_amdgcn_mfma_f32_16x16x32_bf16(
                    ones8, pf[rt], Lacc[rt], 0, 0, 0);
#pragma unroll
            for (int dt = 0; dt < 8; dt++) {
                short8 vf = *(const short8*)(vpp + off + dt * 1024);
#pragma unroll
                for (int rt = 0; rt < 2; rt++)
                    Oacc[rt][dt] = __builtin_amdgcn_mfma_f32_16x16x32_bf16(
                        vf, pf[rt], Oacc[rt][dt], 0, 0, 0);
            }
            __builtin_amdgcn_s_setprio(0);
            __syncthreads();  // next-tile DMA drained; swap buffers
        }
    }

    // epilogue: lane holds q=ln (uniform l), d=dt*16+quad*4+g -> b64 stores
#pragma unroll
    for (int rt = 0; rt < 2; rt++) {
        float inv = 1.f / Lacc[rt][0];
        int row = q0 + wave * 32 + rt * 16 + ln;
        unsigned short* outp = Ab + (size_t)(b * NSEQ + row) * 2048 + h * 128;
#pragma unroll
        for (int dt = 0; dt < 8; dt++) {
            short4v o4;
#pragma unroll
            for (int g = 0; g < 4; g++) o4[g] = (short)f2bf(Oacc[rt][dt][g] * inv);
            *(short4v*)(outp + dt * 16 + quad * 4) = o4;
        }
    }
}

extern "C" void kernel_launch(void* const* d_in, const int* in_sizes, int n_in,
                              void* d_out, int out_size, void* d_ws, size_t ws_size,
                              hipStream_t stream) {
    const float* x    = (const float*)d_in[0];
    const float* cosb = (const float*)d_in[1];
    const float* sinb = (const float*)d_in[2];
    const float* mask = (const float*)d_in[3];
    const float* Wq   = (const float*)d_in[4];
    const float* Wkv  = (const float*)d_in[5];
    const float* Wo   = (const float*)d_in[6];
    const float* bo   = (const float*)d_in[7];
    float* out = (float*)d_out;

    char* ws = (char*)d_ws;
    unsigned short* xb  = (unsigned short*)ws; ws += (size_t)4096 * 2048 * 2;
    unsigned short* W1T = (unsigned short*)ws; ws += (size_t)3072 * 2048 * 2;
    unsigned short* WoT = (unsigned short*)ws; ws += (size_t)2048 * 2048 * 2;
    unsigned short* Qb  = (unsigned short*)ws; ws += (size_t)2 * 16 * 2048 * 128 * 2;
    unsigned short* Kb  = (unsigned short*)ws; ws += (size_t)2 * 4 * 2048 * 128 * 2;
    unsigned short* Vt  = (unsigned short*)ws; ws += (size_t)2 * 4 * 2048 * 128 * 2;
    unsigned short* Ab  = (unsigned short*)ws; ws += (size_t)2 * 2048 * 2048 * 2;
    float* bias2 = (float*)ws;                 ws += (size_t)NB * NSEQ * 4;

    prep_k<<<18436, 256, 0, stream>>>(x, Wq, Wkv, Wo, mask, xb, W1T, WoT, bias2);
    gemm_qkv_rope<<<768, 256, 0, stream>>>(xb, W1T, cosb, sinb, Qb, Kb, Vt);
    attn_k<<<1024, 128, 0, stream>>>(Qb, Kb, Vt, bias2, Ab);
    gemm_bt<<<512, 256, 0, stream>>>(Ab, WoT, out, bo, 4096, 2048, 2048);
}